// Round 1
// baseline (781.249 us; speedup 1.0000x reference)
//
#include <hip/hip_runtime.h>
#include <hip/hip_bf16.h>
#include <math.h>

#define BB 4096
#define NN 128
#define F1D 16
#define HH 64
#define RAWD 128
#define COVD 8

// ---- LDS layout (float offsets) ----
constexpr int S_STRIDE  = 132;                    // 128x128 support, padded
constexpr int X_STRIDE  = 20;                     // 128x16 x_str, padded
constexpr int H_STRIDE  = 68;                     // 128x64 h1/h, padded
constexpr int A1_STRIDE = 17;                     // 128x16 agg1, padded

constexpr int OFF_S    = 0;                       // [128][132] -> also reused for agg2 [128][68]
constexpr int OFF_X    = OFF_S    + 128*S_STRIDE; // 16896
constexpr int OFF_H1   = OFF_X    + 128*X_STRIDE; // 19456
constexpr int OFF_A1   = OFF_H1   + 128*H_STRIDE; // 28160
constexpr int OFF_W1   = OFF_A1   + 128*A1_STRIDE;// 30336  [16][64]
constexpr int OFF_W2   = OFF_W1   + 16*64;        // 31360  [64][64]
constexpr int OFF_DINV = OFF_W2   + 64*64;        // 35456  rowsum -> d_inv [128]
constexpr int OFF_BNS  = OFF_DINV + 128;          // bn scale [128]
constexpr int OFF_BNB  = OFF_BNS  + 128;          // bn shift [128]
constexpr int OFF_SC   = OFF_BNB  + 128;          // scores -> weights [128]
constexpr int OFF_AW   = OFF_SC   + 128;          // attn_w [64]
constexpr int OFF_NW   = OFF_AW   + 64;           // na_w [64]
constexpr int OFF_IN   = OFF_NW   + 64;           // beta_in [200]: raw(128), cov(8), ge(64)
constexpr int OFF_SCAL = OFF_IN   + 200;          // scalars [8]
constexpr int SMEM_FLOATS = OFF_SCAL + 8;         // 36304 floats = 145216 B

__device__ inline float eluf(float x)      { return x > 0.f ? x : expm1f(x); }
__device__ inline float softplusf(float x) { return (x > 20.f) ? x : log1pf(expf(x)); }

__global__ __launch_bounds__(512, 1)
void agp_kernel(const float* __restrict__ x_str, const float* __restrict__ x_raw,
                const float* __restrict__ adj,   const float* __restrict__ x_cov,
                const float* __restrict__ age,
                const float* __restrict__ gc1_w, const float* __restrict__ gc1_b,
                const float* __restrict__ gc2_w, const float* __restrict__ gc2_b,
                const float* __restrict__ bn_gamma, const float* __restrict__ bn_beta,
                const float* __restrict__ bn_mean,  const float* __restrict__ bn_var,
                const float* __restrict__ attn_w, const float* __restrict__ attn_b,
                const float* __restrict__ na_w,   const float* __restrict__ na_b,
                const float* __restrict__ beta_w1, const float* __restrict__ beta_b1,
                const float* __restrict__ beta_w2, const float* __restrict__ beta_b2,
                const float* __restrict__ af_w1,  const float* __restrict__ af_b1,
                const float* __restrict__ af_w2,  const float* __restrict__ af_b2,
                float* __restrict__ out)
{
    extern __shared__ float sm[];
    const int b = blockIdx.x;
    const int t = threadIdx.x;

    // ---------- Phase A0: stage adj(+I) with row sums; stage x_str, weights, vectors ----------
    {
        const float4* adj4 = reinterpret_cast<const float4*>(adj + (size_t)b*NN*NN);
        #pragma unroll
        for (int i = 0; i < 8; ++i) {
            int flat = i*2048 + t*4;
            int row  = flat >> 7;
            int col  = flat & 127;
            float4 v = adj4[flat >> 2];
            int d = row - col;
            if (d == 0) v.x += 1.f; else if (d == 1) v.y += 1.f;
            else if (d == 2) v.z += 1.f; else if (d == 3) v.w += 1.f;
            *reinterpret_cast<float4*>(&sm[OFF_S + row*S_STRIDE + col]) = v;
            float ps = v.x + v.y + v.z + v.w;
            #pragma unroll
            for (int m = 16; m >= 1; m >>= 1) ps += __shfl_xor(ps, m);
            if ((t & 31) == 0) sm[OFF_DINV + row] = ps;   // each row written exactly once
        }
    }
    {   // x_str [128][16] -> LDS padded
        const float4* x4 = reinterpret_cast<const float4*>(x_str + (size_t)b*NN*F1D);
        int flat = t*4;
        int row  = flat >> 4;
        int col  = flat & 15;
        float4 v = x4[t];
        *reinterpret_cast<float4*>(&sm[OFF_X + row*X_STRIDE + col]) = v;
    }
    for (int k = t; k < 16*64; k += 512) sm[OFF_W1 + k] = gc1_w[k];
    for (int k = t; k < 64*64; k += 512) sm[OFF_W2 + k] = gc2_w[k];
    if (t < 128) {
        float g = bn_gamma[t], be = bn_beta[t], mu = bn_mean[t], va = bn_var[t];
        float sc = g * rsqrtf(va + 1e-5f);
        sm[OFF_BNS + t] = sc;
        sm[OFF_BNB + t] = be - mu*sc;
        sm[OFF_IN  + t] = x_raw[(size_t)b*RAWD + t];
    } else if (t < 136) {
        sm[OFF_IN + t] = x_cov[(size_t)b*COVD + (t - 128)];
    } else if (t < 200) {
        int j = t - 136;
        sm[OFF_AW + j] = attn_w[j];
        sm[OFF_NW + j] = na_w[j];
    }
    __syncthreads();

    // ---------- Phase A1: d_inv = rsqrt(rowsum) (rowsum >= 1, never inf) ----------
    if (t < 128) sm[OFF_DINV + t] = rsqrtf(sm[OFF_DINV + t]);
    __syncthreads();

    // ---------- Phase A2: S[n][m] *= d_inv[n]*d_inv[m] in place ----------
    #pragma unroll
    for (int i = 0; i < 8; ++i) {
        int flat = i*2048 + t*4;
        int row  = flat >> 7;
        int col  = flat & 127;
        float  dr = sm[OFF_DINV + row];
        float4 dc = *reinterpret_cast<float4*>(&sm[OFF_DINV + col]);
        float4* p = reinterpret_cast<float4*>(&sm[OFF_S + row*S_STRIDE + col]);
        float4 v = *p;
        v.x *= dr*dc.x; v.y *= dr*dc.y; v.z *= dr*dc.z; v.w *= dr*dc.w;
        *p = v;
    }
    __syncthreads();

    const int n  = t >> 2;       // output row this thread owns
    const int q  = t & 3;        // quarter
    const int j0 = q * 16;

    // ---------- Phase B: agg1 = S @ x   (thread: row n, cols 4q..4q+3) ----------
    {
        float4 acc = {0.f, 0.f, 0.f, 0.f};
        const float* Srow = &sm[OFF_S + n*S_STRIDE];
        #pragma unroll 4
        for (int m = 0; m < NN; ++m) {
            float s = Srow[m];
            float4 xv = *reinterpret_cast<const float4*>(&sm[OFF_X + m*X_STRIDE + 4*q]);
            acc.x += s*xv.x; acc.y += s*xv.y; acc.z += s*xv.z; acc.w += s*xv.w;
        }
        float* a1 = &sm[OFF_A1 + n*A1_STRIDE + 4*q];
        a1[0] = acc.x; a1[1] = acc.y; a1[2] = acc.z; a1[3] = acc.w;
    }
    __syncthreads();

    // ---------- Phase C: h1 = elu(agg1 @ w1 + b1)  (thread: row n, cols j0..j0+15) ----------
    {
        float4 acc[4];
        acc[0] = *reinterpret_cast<const float4*>(&gc1_b[j0 + 0]);
        acc[1] = *reinterpret_cast<const float4*>(&gc1_b[j0 + 4]);
        acc[2] = *reinterpret_cast<const float4*>(&gc1_b[j0 + 8]);
        acc[3] = *reinterpret_cast<const float4*>(&gc1_b[j0 + 12]);
        #pragma unroll
        for (int k = 0; k < F1D; ++k) {
            float a = sm[OFF_A1 + n*A1_STRIDE + k];
            const float* wrow = &sm[OFF_W1 + k*HH + j0];
            #pragma unroll
            for (int u = 0; u < 4; ++u) {
                float4 w = *reinterpret_cast<const float4*>(&wrow[4*u]);
                acc[u].x += a*w.x; acc[u].y += a*w.y; acc[u].z += a*w.z; acc[u].w += a*w.w;
            }
        }
        float* hrow = &sm[OFF_H1 + n*H_STRIDE + j0];
        #pragma unroll
        for (int u = 0; u < 4; ++u) {
            float4 v = acc[u];
            v.x = eluf(v.x); v.y = eluf(v.y); v.z = eluf(v.z); v.w = eluf(v.w);
            *reinterpret_cast<float4*>(&hrow[4*u]) = v;
        }
    }
    __syncthreads();

    // ---------- Phase D: agg2 = S @ h1 (regs) ----------
    float4 acc2[4];
    acc2[0] = {0,0,0,0}; acc2[1] = {0,0,0,0}; acc2[2] = {0,0,0,0}; acc2[3] = {0,0,0,0};
    {
        const float* Srow = &sm[OFF_S + n*S_STRIDE];
        #pragma unroll 2
        for (int m = 0; m < NN; ++m) {
            float s = Srow[m];
            const float* hr = &sm[OFF_H1 + m*H_STRIDE + j0];
            #pragma unroll
            for (int u = 0; u < 4; ++u) {
                float4 h = *reinterpret_cast<const float4*>(&hr[4*u]);
                acc2[u].x += s*h.x; acc2[u].y += s*h.y; acc2[u].z += s*h.z; acc2[u].w += s*h.w;
            }
        }
    }
    __syncthreads();               // all reads of S done
    {   // park agg2 in the (dead) S buffer, stride 68
        float* a2 = &sm[OFF_S + n*H_STRIDE + j0];
        *reinterpret_cast<float4*>(&a2[0])  = acc2[0];
        *reinterpret_cast<float4*>(&a2[4])  = acc2[1];
        *reinterpret_cast<float4*>(&a2[8])  = acc2[2];
        *reinterpret_cast<float4*>(&a2[12]) = acc2[3];
    }
    __syncthreads();

    // ---------- Phase E: h = BN(elu(agg2 @ w2 + b2)) -> overwrite h1 buffer ----------
    {
        float4 acc[4];
        acc[0] = *reinterpret_cast<const float4*>(&gc2_b[j0 + 0]);
        acc[1] = *reinterpret_cast<const float4*>(&gc2_b[j0 + 4]);
        acc[2] = *reinterpret_cast<const float4*>(&gc2_b[j0 + 8]);
        acc[3] = *reinterpret_cast<const float4*>(&gc2_b[j0 + 12]);
        #pragma unroll 4
        for (int k = 0; k < HH; ++k) {
            float a = sm[OFF_S + n*H_STRIDE + k];
            const float* wrow = &sm[OFF_W2 + k*HH + j0];
            #pragma unroll
            for (int u = 0; u < 4; ++u) {
                float4 w = *reinterpret_cast<const float4*>(&wrow[4*u]);
                acc[u].x += a*w.x; acc[u].y += a*w.y; acc[u].z += a*w.z; acc[u].w += a*w.w;
            }
        }
        float bs = sm[OFF_BNS + n], bb = sm[OFF_BNB + n];
        float* hrow = &sm[OFF_H1 + n*H_STRIDE + j0];
        #pragma unroll
        for (int u = 0; u < 4; ++u) {
            float4 v = acc[u];
            v.x = eluf(v.x)*bs + bb; v.y = eluf(v.y)*bs + bb;
            v.z = eluf(v.z)*bs + bb; v.w = eluf(v.w)*bs + bb;
            *reinterpret_cast<float4*>(&hrow[4*u]) = v;
        }
    }
    __syncthreads();

    // ---------- Phase F1: attention scores + alpha_node ----------
    if (t < 128) {
        float accA = attn_b[0], accN = na_b[0];
        const float* hrow = &sm[OFF_H1 + t*H_STRIDE];
        #pragma unroll 8
        for (int jj = 0; jj < HH; ++jj) {
            int j = (jj + t) & 63;                  // rotate to dodge bank conflicts
            float hv = hrow[j];
            accA += hv * sm[OFF_AW + j];
            accN += hv * sm[OFF_NW + j];
        }
        sm[OFF_SC + t] = accA;
        out[12288 + (size_t)b*NN + t] = softplusf(accN);   // alpha_node
    }
    __syncthreads();

    // ---------- Phase F2: softmax over n (wave 0) ----------
    if (t < 64) {
        float s0 = sm[OFF_SC + t], s1 = sm[OFF_SC + 64 + t];
        float mx = fmaxf(s0, s1);
        #pragma unroll
        for (int m = 32; m >= 1; m >>= 1) mx = fmaxf(mx, __shfl_xor(mx, m));
        float e0 = expf(s0 - mx), e1 = expf(s1 - mx);
        float sum = e0 + e1;
        #pragma unroll
        for (int m = 32; m >= 1; m >>= 1) sum += __shfl_xor(sum, m);
        float inv = 1.f / sum;
        float w0 = e0*inv, w1 = e1*inv;
        sm[OFF_SC + t]      = w0;
        sm[OFF_SC + 64 + t] = w1;
        out[536576 + (size_t)b*NN + t]      = w0;          // weights
        out[536576 + (size_t)b*NN + 64 + t] = w1;
    }
    __syncthreads();

    // ---------- Phase F3: graph_emb (wave 0) ----------
    if (t < 64) {
        float ge = 0.f;
        #pragma unroll 8
        for (int m = 0; m < NN; ++m)
            ge += sm[OFF_H1 + m*H_STRIDE + t] * sm[OFF_SC + m];
        sm[OFF_IN + 136 + t] = ge;
    }
    __syncthreads();

    // ---------- Phase G: the two small MLPs (wave 0 = beta, wave 1 lanes 0..31 = decay) ----------
    if (t < 64) {
        float acc = beta_b1[t];
        for (int i = 0; i < 200; ++i)
            acc += sm[OFF_IN + i] * beta_w1[i*64 + t];
        float p = tanhf(acc) * beta_w2[t];
        #pragma unroll
        for (int m = 32; m >= 1; m >>= 1) p += __shfl_xor(p, m);
        if (t == 0) sm[OFF_SCAL + 0] = 1.f / (1.f + expf(-(p + beta_b2[0])));
    } else if (t < 96) {
        int u = t - 64;
        float acc = af_b1[u];
        for (int i = 0; i < 192; ++i) {
            float inv = (i < 64) ? sm[OFF_IN + 136 + i] : sm[OFF_IN + (i - 64)];
            acc += inv * af_w1[i*32 + u];
        }
        float p = fmaxf(acc, 0.f) * af_w2[u];
        #pragma unroll
        for (int m = 16; m >= 1; m >>= 1) p += __shfl_xor(p, m);
        if (u == 0) sm[OFF_SCAL + 1] = softplusf(p + af_b2[0]);
    }
    __syncthreads();

    if (t == 0) {
        float bet = sm[OFF_SCAL + 0], dec = sm[OFF_SCAL + 1];
        out[b]        = bet * (1.f - dec * age[b]);   // pred
        out[4096 + b] = bet;                          // beta
        out[8192 + b] = dec;                          // decay_rate
    }
}

extern "C" void kernel_launch(void* const* d_in, const int* in_sizes, int n_in,
                              void* d_out, int out_size, void* d_ws, size_t ws_size,
                              hipStream_t stream) {
    (void)in_sizes; (void)n_in; (void)out_size; (void)d_ws; (void)ws_size;
    const float* x_str   = (const float*)d_in[0];
    const float* x_raw   = (const float*)d_in[1];
    const float* adj     = (const float*)d_in[2];
    const float* x_cov   = (const float*)d_in[3];
    const float* age     = (const float*)d_in[4];
    const float* gc1_w   = (const float*)d_in[5];
    const float* gc1_b   = (const float*)d_in[6];
    const float* gc2_w   = (const float*)d_in[7];
    const float* gc2_b   = (const float*)d_in[8];
    const float* bn_g    = (const float*)d_in[9];
    const float* bn_b    = (const float*)d_in[10];
    const float* bn_m    = (const float*)d_in[11];
    const float* bn_v    = (const float*)d_in[12];
    const float* attn_w  = (const float*)d_in[13];
    const float* attn_b  = (const float*)d_in[14];
    const float* na_w    = (const float*)d_in[15];
    const float* na_b    = (const float*)d_in[16];
    const float* beta_w1 = (const float*)d_in[17];
    const float* beta_b1 = (const float*)d_in[18];
    const float* beta_w2 = (const float*)d_in[19];
    const float* beta_b2 = (const float*)d_in[20];
    const float* af_w1   = (const float*)d_in[21];
    const float* af_b1   = (const float*)d_in[22];
    const float* af_w2   = (const float*)d_in[23];
    const float* af_b2   = (const float*)d_in[24];
    float* out = (float*)d_out;

    size_t smem = (size_t)SMEM_FLOATS * sizeof(float);   // 145216 B
    (void)hipFuncSetAttribute((const void*)agp_kernel,
                              hipFuncAttributeMaxDynamicSharedMemorySize, (int)smem);
    agp_kernel<<<BB, 512, smem, stream>>>(
        x_str, x_raw, adj, x_cov, age,
        gc1_w, gc1_b, gc2_w, gc2_b,
        bn_g, bn_b, bn_m, bn_v,
        attn_w, attn_b, na_w, na_b,
        beta_w1, beta_b1, beta_w2, beta_b2,
        af_w1, af_b1, af_w2, af_b2,
        out);
}

// Round 2
// 346.650 us; speedup vs baseline: 2.2537x; 2.2537x over previous
//
#include <hip/hip_runtime.h>
#include <hip/hip_bf16.h>
#include <math.h>

#define BB 4096
#define NN 128

typedef __attribute__((ext_vector_type(8))) __bf16 bf16x8;
typedef __attribute__((ext_vector_type(4))) __bf16 bf16x4;
typedef __attribute__((ext_vector_type(4))) float f32x4;

// ---- LDS byte offsets (all 16B aligned; row strides multiples of 8 bf16 = 16B) ----
constexpr int OFF_S    = 0;        // bf16 [128][136] A_hat ; after M3 reused as f32 h [128][68]
constexpr int OFF_XT   = 34816;    // bf16 [16][136]  (d_inv ⊙ x)^T
constexpr int OFF_W1T  = 39168;    // bf16 [64][40]   W1^T, k 16..31 zero-padded
constexpr int OFF_W2T  = 44288;    // bf16 [64][72]   W2^T
constexpr int OFF_AGG1 = 53504;    // bf16 [128][40]  agg1, cols 16..31 zero-padded
constexpr int OFF_H1T  = 63744;    // bf16 [64][136]  (d_inv ⊙ h1)^T
constexpr int OFF_AGG2 = 81152;    // bf16 [128][72]
constexpr int OFF_RS   = 99584;    // f32 [128] rowsum
constexpr int OFF_DINV = 100096;   // f32 [128]
constexpr int OFF_BNS  = 100608;   // f32 [128]
constexpr int OFF_BNB  = 101120;   // f32 [128]
constexpr int OFF_SC   = 101632;   // f32 [128] attn scores -> weights
constexpr int OFF_AW   = 102144;   // f32 [64]
constexpr int OFF_NW   = 102400;   // f32 [64]
constexpr int OFF_B1   = 102656;   // f32 [64]
constexpr int OFF_B2   = 102912;   // f32 [64]
constexpr int OFF_IN   = 103168;   // f32 [200]: x_raw(128), x_cov(8), graph_emb(64)
constexpr int OFF_SCAL = 103968;   // f32 [8]
constexpr int SMEM_BYTES = 104000;

__device__ inline float eluf(float x)      { return x > 0.f ? x : expm1f(x); }
__device__ inline float softplusf(float x) { return (x > 20.f) ? x : log1pf(expf(x)); }

__global__ __launch_bounds__(512, 1)
void agp_kernel(const float* __restrict__ x_str, const float* __restrict__ x_raw,
                const float* __restrict__ adj,   const float* __restrict__ x_cov,
                const float* __restrict__ age,
                const float* __restrict__ gc1_w, const float* __restrict__ gc1_b,
                const float* __restrict__ gc2_w, const float* __restrict__ gc2_b,
                const float* __restrict__ bn_gamma, const float* __restrict__ bn_beta,
                const float* __restrict__ bn_mean,  const float* __restrict__ bn_var,
                const float* __restrict__ attn_w, const float* __restrict__ attn_b,
                const float* __restrict__ na_w,   const float* __restrict__ na_b,
                const float* __restrict__ beta_w1, const float* __restrict__ beta_b1,
                const float* __restrict__ beta_w2, const float* __restrict__ beta_b2,
                const float* __restrict__ af_w1,  const float* __restrict__ af_b1,
                const float* __restrict__ af_w2,  const float* __restrict__ af_b2,
                float* __restrict__ out)
{
    extern __shared__ __align__(16) char smraw[];
    __bf16* S   = (__bf16*)(smraw + OFF_S);
    __bf16* XT  = (__bf16*)(smraw + OFF_XT);
    __bf16* W1T = (__bf16*)(smraw + OFF_W1T);
    __bf16* W2T = (__bf16*)(smraw + OFF_W2T);
    __bf16* AG1 = (__bf16*)(smraw + OFF_AGG1);
    __bf16* H1T = (__bf16*)(smraw + OFF_H1T);
    __bf16* AG2 = (__bf16*)(smraw + OFF_AGG2);
    float* RS   = (float*)(smraw + OFF_RS);
    float* DINV = (float*)(smraw + OFF_DINV);
    float* BNS  = (float*)(smraw + OFF_BNS);
    float* BNB  = (float*)(smraw + OFF_BNB);
    float* SCv  = (float*)(smraw + OFF_SC);
    float* AW   = (float*)(smraw + OFF_AW);
    float* NWv  = (float*)(smraw + OFF_NW);
    float* B1v  = (float*)(smraw + OFF_B1);
    float* B2v  = (float*)(smraw + OFF_B2);
    float* INv  = (float*)(smraw + OFF_IN);
    float* SCAL = (float*)(smraw + OFF_SCAL);
    float* Hf   = (float*)(smraw + OFF_S);     // overlay: live after M3

    const int b = blockIdx.x;
    const int t = threadIdx.x;
    const int w  = t >> 6;
    const int lane = t & 63;
    const int ll = lane & 15;      // N-side / row-within-tile index
    const int lh = lane >> 4;      // 0..3

    // ---------------- Phase A0: stage everything ----------------
    float4 xv;
    {
        const float4* adj4 = reinterpret_cast<const float4*>(adj + (size_t)b*NN*NN);
        #pragma unroll
        for (int i = 0; i < 8; ++i) {
            int flat = i*2048 + t*4;
            int row  = flat >> 7;
            int col  = flat & 127;
            float4 v = adj4[flat >> 2];
            int d = row - col;
            if (d == 0) v.x += 1.f; else if (d == 1) v.y += 1.f;
            else if (d == 2) v.z += 1.f; else if (d == 3) v.w += 1.f;
            bf16x4 pv;
            pv[0] = (__bf16)v.x; pv[1] = (__bf16)v.y;
            pv[2] = (__bf16)v.z; pv[3] = (__bf16)v.w;
            *reinterpret_cast<bf16x4*>(&S[row*136 + col]) = pv;
            float ps = v.x + v.y + v.z + v.w;
            #pragma unroll
            for (int m = 16; m >= 1; m >>= 1) ps += __shfl_xor(ps, m);
            if ((t & 31) == 0) RS[row] = ps;      // rowsum (f32, pre-truncation)
        }
        xv = reinterpret_cast<const float4*>(x_str + (size_t)b*NN*16)[t];

        for (int idx = t; idx < 1024; idx += 512) {            // W1^T
            int k = idx >> 6, j = idx & 63;
            W1T[j*40 + k] = (__bf16)gc1_w[idx];
        }
        for (int idx = t; idx < 1024; idx += 512) {            // W1^T zero pad k=16..31
            int j = idx >> 4, k = idx & 15;
            W1T[j*40 + 16 + k] = (__bf16)0.f;
        }
        for (int idx = t; idx < 4096; idx += 512) {            // W2^T
            int k = idx >> 6, j = idx & 63;
            W2T[j*72 + k] = (__bf16)gc2_w[idx];
        }
        for (int idx = t; idx < 2048; idx += 512) {            // agg1 zero pad cols 16..31
            int r = idx >> 4, c = idx & 15;
            AG1[r*40 + 16 + c] = (__bf16)0.f;
        }
        if (t < 128) {
            float g = bn_gamma[t], be = bn_beta[t], mu = bn_mean[t], va = bn_var[t];
            float sc = g * rsqrtf(va + 1e-5f);
            BNS[t] = sc;
            BNB[t] = be - mu*sc;
            INv[t] = x_raw[(size_t)b*128 + t];
        } else if (t < 136) {
            INv[t] = x_cov[(size_t)b*8 + (t - 128)];
        } else if (t < 200) {
            int j = t - 136;
            AW[j] = attn_w[j];
            NWv[j] = na_w[j];
        } else if (t < 264) {
            B1v[t-200] = gc1_b[t-200];
        } else if (t < 328) {
            B2v[t-264] = gc2_b[t-264];
        }
    }
    __syncthreads();

    // ---------------- Phase A1: d_inv; XT = (d_inv ⊙ x)^T (bf16) ----------------
    {
        int m = t >> 2;
        float dm = rsqrtf(RS[m]);             // rowsum >= 1, never inf
        if (t < 128) DINV[t] = rsqrtf(RS[t]);
        int c0 = (t & 3) * 4;
        XT[(c0+0)*136 + m] = (__bf16)(xv.x * dm);
        XT[(c0+1)*136 + m] = (__bf16)(xv.y * dm);
        XT[(c0+2)*136 + m] = (__bf16)(xv.z * dm);
        XT[(c0+3)*136 + m] = (__bf16)(xv.w * dm);
    }
    __syncthreads();

    // ---------------- M1: agg1 = d_r ⊙ (A_hat @ (d_c ⊙ x)) ----------------
    {
        f32x4 acc = {0.f, 0.f, 0.f, 0.f};
        #pragma unroll
        for (int kt = 0; kt < 4; ++kt) {
            bf16x8 a  = *reinterpret_cast<const bf16x8*>(&S[(16*w + ll)*136 + kt*32 + 8*lh]);
            bf16x8 bf = *reinterpret_cast<const bf16x8*>(&XT[ll*136 + kt*32 + 8*lh]);
            acc = __builtin_amdgcn_mfma_f32_16x16x32_bf16(a, bf, acc, 0, 0, 0);
        }
        #pragma unroll
        for (int r = 0; r < 4; ++r) {
            int row = 16*w + 4*lh + r;
            AG1[row*40 + ll] = (__bf16)(acc[r] * DINV[row]);
        }
    }
    __syncthreads();

    // ---------------- M2: h1 = elu(agg1 @ W1 + b1); store (d_inv ⊙ h1)^T ----------------
    {
        bf16x8 a = *reinterpret_cast<const bf16x8*>(&AG1[(16*w + ll)*40 + 8*lh]);
        #pragma unroll
        for (int jt = 0; jt < 4; ++jt) {
            bf16x8 bf = *reinterpret_cast<const bf16x8*>(&W1T[(16*jt + ll)*40 + 8*lh]);
            f32x4 z = {0.f, 0.f, 0.f, 0.f};
            f32x4 acc = __builtin_amdgcn_mfma_f32_16x16x32_bf16(a, bf, z, 0, 0, 0);
            float bj = B1v[16*jt + ll];
            #pragma unroll
            for (int r = 0; r < 4; ++r) {
                int m = 16*w + 4*lh + r;
                float v = eluf(acc[r] + bj);
                H1T[(16*jt + ll)*136 + m] = (__bf16)(v * DINV[m]);
            }
        }
    }
    __syncthreads();

    // ---------------- M3: agg2 = d_r ⊙ (A_hat @ (d_c ⊙ h1)) ----------------
    {
        f32x4 acc2[4];
        #pragma unroll
        for (int jt = 0; jt < 4; ++jt) acc2[jt] = (f32x4){0.f, 0.f, 0.f, 0.f};
        #pragma unroll
        for (int kt = 0; kt < 4; ++kt) {
            bf16x8 a = *reinterpret_cast<const bf16x8*>(&S[(16*w + ll)*136 + kt*32 + 8*lh]);
            #pragma unroll
            for (int jt = 0; jt < 4; ++jt) {
                bf16x8 bf = *reinterpret_cast<const bf16x8*>(&H1T[(16*jt + ll)*136 + kt*32 + 8*lh]);
                acc2[jt] = __builtin_amdgcn_mfma_f32_16x16x32_bf16(a, bf, acc2[jt], 0, 0, 0);
            }
        }
        #pragma unroll
        for (int jt = 0; jt < 4; ++jt) {
            #pragma unroll
            for (int r = 0; r < 4; ++r) {
                int row = 16*w + 4*lh + r;
                AG2[row*72 + 16*jt + ll] = (__bf16)(acc2[jt][r] * DINV[row]);
            }
        }
    }
    __syncthreads();   // also fences last reads of S before Hf overlay write

    // ---------------- M4: h = BN(elu(agg2 @ W2 + b2)) -> f32, overlays S ----------------
    {
        f32x4 acc4[4];
        #pragma unroll
        for (int jt = 0; jt < 4; ++jt) acc4[jt] = (f32x4){0.f, 0.f, 0.f, 0.f};
        #pragma unroll
        for (int kt = 0; kt < 2; ++kt) {
            bf16x8 a = *reinterpret_cast<const bf16x8*>(&AG2[(16*w + ll)*72 + kt*32 + 8*lh]);
            #pragma unroll
            for (int jt = 0; jt < 4; ++jt) {
                bf16x8 bf = *reinterpret_cast<const bf16x8*>(&W2T[(16*jt + ll)*72 + kt*32 + 8*lh]);
                acc4[jt] = __builtin_amdgcn_mfma_f32_16x16x32_bf16(a, bf, acc4[jt], 0, 0, 0);
            }
        }
        #pragma unroll
        for (int jt = 0; jt < 4; ++jt) {
            float bj = B2v[16*jt + ll];
            #pragma unroll
            for (int r = 0; r < 4; ++r) {
                int row = 16*w + 4*lh + r;
                float v = eluf(acc4[jt][r] + bj) * BNS[row] + BNB[row];
                Hf[row*68 + 16*jt + ll] = v;
            }
        }
    }
    __syncthreads();

    // ---------------- F1: attention scores + alpha_node ----------------
    if (t < 128) {
        float accA = attn_b[0], accN = na_b[0];
        const float* hrow = &Hf[t*68];
        #pragma unroll 8
        for (int jj = 0; jj < 64; ++jj) {
            int j = (jj + t) & 63;
            float hv = hrow[j];
            accA += hv * AW[j];
            accN += hv * NWv[j];
        }
        SCv[t] = accA;
        out[12288 + (size_t)b*NN + t] = softplusf(accN);   // alpha_node
    }
    __syncthreads();

    // ---------------- F2: softmax over nodes (wave 0) ----------------
    if (t < 64) {
        float s0 = SCv[t], s1 = SCv[64 + t];
        float mx = fmaxf(s0, s1);
        #pragma unroll
        for (int m = 32; m >= 1; m >>= 1) mx = fmaxf(mx, __shfl_xor(mx, m));
        float e0 = expf(s0 - mx), e1 = expf(s1 - mx);
        float sum = e0 + e1;
        #pragma unroll
        for (int m = 32; m >= 1; m >>= 1) sum += __shfl_xor(sum, m);
        float inv = 1.f / sum;
        float w0 = e0*inv, w1 = e1*inv;
        SCv[t]      = w0;
        SCv[64 + t] = w1;
        out[536576 + (size_t)b*NN + t]      = w0;          // weights
        out[536576 + (size_t)b*NN + 64 + t] = w1;
    }
    __syncthreads();

    // ---------------- F3: graph_emb (wave 0) ----------------
    if (t < 64) {
        float ge = 0.f;
        #pragma unroll 8
        for (int m = 0; m < NN; ++m)
            ge += Hf[m*68 + t] * SCv[m];
        INv[136 + t] = ge;
    }
    __syncthreads();

    // ---------------- G: small MLPs ----------------
    if (t < 64) {
        float acc = beta_b1[t];
        for (int i = 0; i < 200; ++i)
            acc += INv[i] * beta_w1[i*64 + t];
        float p = tanhf(acc) * beta_w2[t];
        #pragma unroll
        for (int m = 32; m >= 1; m >>= 1) p += __shfl_xor(p, m);
        if (t == 0) SCAL[0] = 1.f / (1.f + expf(-(p + beta_b2[0])));
    } else if (t < 96) {
        int u = t - 64;
        float acc = af_b1[u];
        for (int i = 0; i < 192; ++i) {
            float inv = (i < 64) ? INv[136 + i] : INv[i - 64];
            acc += inv * af_w1[i*32 + u];
        }
        float p = fmaxf(acc, 0.f) * af_w2[u];
        #pragma unroll
        for (int m = 16; m >= 1; m >>= 1) p += __shfl_xor(p, m);
        if (u == 0) SCAL[1] = softplusf(p + af_b2[0]);
    }
    __syncthreads();

    if (t == 0) {
        float bet = SCAL[0], dec = SCAL[1];
        out[b]        = bet * (1.f - dec * age[b]);   // pred
        out[4096 + b] = bet;                          // beta
        out[8192 + b] = dec;                          // decay_rate
    }
}

extern "C" void kernel_launch(void* const* d_in, const int* in_sizes, int n_in,
                              void* d_out, int out_size, void* d_ws, size_t ws_size,
                              hipStream_t stream) {
    (void)in_sizes; (void)n_in; (void)out_size; (void)d_ws; (void)ws_size;
    const float* x_str   = (const float*)d_in[0];
    const float* x_raw   = (const float*)d_in[1];
    const float* adj     = (const float*)d_in[2];
    const float* x_cov   = (const float*)d_in[3];
    const float* age     = (const float*)d_in[4];
    const float* gc1_w   = (const float*)d_in[5];
    const float* gc1_b   = (const float*)d_in[6];
    const float* gc2_w   = (const float*)d_in[7];
    const float* gc2_b   = (const float*)d_in[8];
    const float* bn_g    = (const float*)d_in[9];
    const float* bn_b    = (const float*)d_in[10];
    const float* bn_m    = (const float*)d_in[11];
    const float* bn_v    = (const float*)d_in[12];
    const float* attn_w  = (const float*)d_in[13];
    const float* attn_b  = (const float*)d_in[14];
    const float* na_w    = (const float*)d_in[15];
    const float* na_b    = (const float*)d_in[16];
    const float* beta_w1 = (const float*)d_in[17];
    const float* beta_b1 = (const float*)d_in[18];
    const float* beta_w2 = (const float*)d_in[19];
    const float* beta_b2 = (const float*)d_in[20];
    const float* af_w1   = (const float*)d_in[21];
    const float* af_b1   = (const float*)d_in[22];
    const float* af_w2   = (const float*)d_in[23];
    const float* af_b2   = (const float*)d_in[24];
    float* out = (float*)d_out;

    (void)hipFuncSetAttribute((const void*)agp_kernel,
                              hipFuncAttributeMaxDynamicSharedMemorySize, SMEM_BYTES);
    agp_kernel<<<BB, 512, SMEM_BYTES, stream>>>(
        x_str, x_raw, adj, x_cov, age,
        gc1_w, gc1_b, gc2_w, gc2_b,
        bn_g, bn_b, bn_m, bn_v,
        attn_w, attn_b, na_w, na_b,
        beta_w1, beta_b1, beta_w2, beta_b2,
        af_w1, af_b1, af_w2, af_b2,
        out);
}

// Round 3
// 184.635 us; speedup vs baseline: 4.2313x; 1.8775x over previous
//
#include <hip/hip_runtime.h>
#include <hip/hip_bf16.h>
#include <math.h>

#define BB 4096
#define NN 128

typedef __attribute__((ext_vector_type(8))) __bf16 bf16x8;
typedef __attribute__((ext_vector_type(4))) __bf16 bf16x4;
typedef __attribute__((ext_vector_type(4))) float f32x4;

// ---- LDS byte offsets (all 16B aligned) ----
// S region [0, 34816): bf16 A_hat [128][136]; after M4 overlaid by f32 h [128][68]
// U1 region [34816, 54528): XT + W1T + AG1  -> overlaid by AG2 (M3/M4) -> GE/GP/AP (tail)
// H  region [54528, 71936): H1T (M2/M3)     -> overlaid by W2T (M4)
constexpr int OFF_S    = 0;
constexpr int OFF_XT   = 34816;   // bf16 [16][136]  (d_inv ⊙ x)^T          (dead after M1)
constexpr int OFF_W1T  = 39168;   // bf16 [64][40]   W1^T, k16..31 zeroed    (dead after M2)
constexpr int OFF_AG1  = 44288;   // bf16 [128][40]  agg1, c16..31 zeroed    (dead after M2)
constexpr int OFF_AG2  = 34816;   // bf16 [128][72]  (written M3, read M4)
constexpr int OFF_GE   = 34816;   // f32 [8][64] graph-emb partials (tail)
constexpr int OFF_GP   = 36864;   // f32 [4][64] beta-MLP partials
constexpr int OFF_AP   = 37888;   // f32 [4][32] decay-MLP partials
constexpr int OFF_H1T  = 54528;   // bf16 [64][136]  (d_inv ⊙ h1)^T         (dead after M3)
constexpr int OFF_W2T  = 54528;   // bf16 [64][72]   W2^T (written post-M3, read M4)
constexpr int OFF_RS   = 71936;   // f32 [128]
constexpr int OFF_DINV = 72448;   // f32 [128]
constexpr int OFF_BNS  = 72960;   // f32 [128]
constexpr int OFF_BNB  = 73472;   // f32 [128]
constexpr int OFF_SC   = 73984;   // f32 [128]
constexpr int OFF_AW   = 74496;   // f32 [64]
constexpr int OFF_NW   = 74752;   // f32 [64]
constexpr int OFF_B1   = 75008;   // f32 [64]
constexpr int OFF_B2   = 75264;   // f32 [64]
constexpr int OFF_IN   = 75520;   // f32 [200]: x_raw(128), x_cov(8), graph_emb(64)
constexpr int OFF_SCAL = 76320;   // f32 [8]
constexpr int SMEM_BYTES = 76352; // 74.6 KB -> 2 blocks/CU

__device__ inline float eluf(float x)      { return x > 0.f ? x : expm1f(x); }
__device__ inline float softplusf(float x) { return (x > 20.f) ? x : log1pf(expf(x)); }

__global__ __launch_bounds__(512, 4)
void agp_kernel(const float* __restrict__ x_str, const float* __restrict__ x_raw,
                const float* __restrict__ adj,   const float* __restrict__ x_cov,
                const float* __restrict__ age,
                const float* __restrict__ gc1_w, const float* __restrict__ gc1_b,
                const float* __restrict__ gc2_w, const float* __restrict__ gc2_b,
                const float* __restrict__ bn_gamma, const float* __restrict__ bn_beta,
                const float* __restrict__ bn_mean,  const float* __restrict__ bn_var,
                const float* __restrict__ attn_w, const float* __restrict__ attn_b,
                const float* __restrict__ na_w,   const float* __restrict__ na_b,
                const float* __restrict__ beta_w1, const float* __restrict__ beta_b1,
                const float* __restrict__ beta_w2, const float* __restrict__ beta_b2,
                const float* __restrict__ af_w1,  const float* __restrict__ af_b1,
                const float* __restrict__ af_w2,  const float* __restrict__ af_b2,
                float* __restrict__ out)
{
    extern __shared__ __align__(16) char smraw[];
    __bf16* S   = (__bf16*)(smraw + OFF_S);
    __bf16* XT  = (__bf16*)(smraw + OFF_XT);
    __bf16* W1T = (__bf16*)(smraw + OFF_W1T);
    __bf16* AG1 = (__bf16*)(smraw + OFF_AG1);
    __bf16* AG2 = (__bf16*)(smraw + OFF_AG2);
    __bf16* H1T = (__bf16*)(smraw + OFF_H1T);
    __bf16* W2T = (__bf16*)(smraw + OFF_W2T);
    float* GEp  = (float*)(smraw + OFF_GE);
    float* GP   = (float*)(smraw + OFF_GP);
    float* AP   = (float*)(smraw + OFF_AP);
    float* RS   = (float*)(smraw + OFF_RS);
    float* DINV = (float*)(smraw + OFF_DINV);
    float* BNS  = (float*)(smraw + OFF_BNS);
    float* BNB  = (float*)(smraw + OFF_BNB);
    float* SCv  = (float*)(smraw + OFF_SC);
    float* AW   = (float*)(smraw + OFF_AW);
    float* NWv  = (float*)(smraw + OFF_NW);
    float* B1v  = (float*)(smraw + OFF_B1);
    float* B2v  = (float*)(smraw + OFF_B2);
    float* INv  = (float*)(smraw + OFF_IN);
    float* SCAL = (float*)(smraw + OFF_SCAL);
    float* Hf   = (float*)(smraw + OFF_S);     // overlay: live after M4

    const int b = blockIdx.x;
    const int t = threadIdx.x;
    const int w    = t >> 6;
    const int lane = t & 63;
    const int ll = lane & 15;
    const int lh = lane >> 4;

    // ---------------- Phase A0: stage everything ----------------
    float4 xv;
    float w2reg[8];
    {
        const float4* adj4 = reinterpret_cast<const float4*>(adj + (size_t)b*NN*NN);
        #pragma unroll
        for (int i = 0; i < 8; ++i) {
            int flat = i*2048 + t*4;
            int row  = flat >> 7;
            int col  = flat & 127;
            float4 v = adj4[flat >> 2];
            int d = row - col;
            if (d == 0) v.x += 1.f; else if (d == 1) v.y += 1.f;
            else if (d == 2) v.z += 1.f; else if (d == 3) v.w += 1.f;
            bf16x4 pv;
            pv[0] = (__bf16)v.x; pv[1] = (__bf16)v.y;
            pv[2] = (__bf16)v.z; pv[3] = (__bf16)v.w;
            *reinterpret_cast<bf16x4*>(&S[row*136 + col]) = pv;
            float ps = v.x + v.y + v.z + v.w;
            #pragma unroll
            for (int m = 16; m >= 1; m >>= 1) ps += __shfl_xor(ps, m);
            if ((t & 31) == 0) RS[row] = ps;      // rowsum (f32, pre-truncation)
        }
        xv = reinterpret_cast<const float4*>(x_str + (size_t)b*NN*16)[t];

        {   // W2 -> registers (transposed gather; L2-resident after first blocks)
            int j = t >> 3, kb = (t & 7) * 8;
            #pragma unroll
            for (int i = 0; i < 8; ++i) w2reg[i] = gc2_w[(kb + i)*64 + j];
        }
        for (int idx = t; idx < 1024; idx += 512) {            // W1^T
            int k = idx >> 6, j = idx & 63;
            W1T[j*40 + k] = (__bf16)gc1_w[idx];
        }
        for (int idx = t; idx < 1024; idx += 512) {            // W1^T zero pad k=16..31
            int j = idx >> 4, k = idx & 15;
            W1T[j*40 + 16 + k] = (__bf16)0.f;
        }
        for (int idx = t; idx < 2048; idx += 512) {            // agg1 zero pad cols 16..31
            int r = idx >> 4, c = idx & 15;
            AG1[r*40 + 16 + c] = (__bf16)0.f;
        }
        if (t < 128) {
            float g = bn_gamma[t], be = bn_beta[t], mu = bn_mean[t], va = bn_var[t];
            float sc = g * rsqrtf(va + 1e-5f);
            BNS[t] = sc;
            BNB[t] = be - mu*sc;
            INv[t] = x_raw[(size_t)b*128 + t];
        } else if (t < 136) {
            INv[t] = x_cov[(size_t)b*8 + (t - 128)];
        } else if (t < 200) {
            int j = t - 136;
            AW[j] = attn_w[j];
            NWv[j] = na_w[j];
        } else if (t < 264) {
            B1v[t-200] = gc1_b[t-200];
        } else if (t < 328) {
            B2v[t-264] = gc2_b[t-264];
        }
    }
    __syncthreads();

    // ---------------- Phase A1: d_inv; XT = (d_inv ⊙ x)^T (bf16) ----------------
    {
        int m = t >> 2;
        float dm = rsqrtf(RS[m]);             // rowsum >= 1, never inf
        if (t < 128) DINV[t] = rsqrtf(RS[t]);
        int c0 = (t & 3) * 4;
        XT[(c0+0)*136 + m] = (__bf16)(xv.x * dm);
        XT[(c0+1)*136 + m] = (__bf16)(xv.y * dm);
        XT[(c0+2)*136 + m] = (__bf16)(xv.z * dm);
        XT[(c0+3)*136 + m] = (__bf16)(xv.w * dm);
    }
    __syncthreads();

    // ---------------- M1: agg1 = d_r ⊙ (A_hat @ (d_c ⊙ x)) ----------------
    {
        f32x4 acc = {0.f, 0.f, 0.f, 0.f};
        #pragma unroll
        for (int kt = 0; kt < 4; ++kt) {
            bf16x8 a  = *reinterpret_cast<const bf16x8*>(&S[(16*w + ll)*136 + kt*32 + 8*lh]);
            bf16x8 bf = *reinterpret_cast<const bf16x8*>(&XT[ll*136 + kt*32 + 8*lh]);
            acc = __builtin_amdgcn_mfma_f32_16x16x32_bf16(a, bf, acc, 0, 0, 0);
        }
        #pragma unroll
        for (int r = 0; r < 4; ++r) {
            int row = 16*w + 4*lh + r;
            AG1[row*40 + ll] = (__bf16)(acc[r] * DINV[row]);
        }
    }
    __syncthreads();

    // ---------------- M2: h1 = elu(agg1 @ W1 + b1); store (d_inv ⊙ h1)^T ----------------
    {
        bf16x8 a = *reinterpret_cast<const bf16x8*>(&AG1[(16*w + ll)*40 + 8*lh]);
        #pragma unroll
        for (int jt = 0; jt < 4; ++jt) {
            bf16x8 bf = *reinterpret_cast<const bf16x8*>(&W1T[(16*jt + ll)*40 + 8*lh]);
            f32x4 z = {0.f, 0.f, 0.f, 0.f};
            f32x4 acc = __builtin_amdgcn_mfma_f32_16x16x32_bf16(a, bf, z, 0, 0, 0);
            float bj = B1v[16*jt + ll];
            #pragma unroll
            for (int r = 0; r < 4; ++r) {
                int m = 16*w + 4*lh + r;
                float v = eluf(acc[r] + bj);
                H1T[(16*jt + ll)*136 + m] = (__bf16)(v * DINV[m]);
            }
        }
    }
    __syncthreads();

    // ---------------- M3: agg2 = d_r ⊙ (A_hat @ (d_c ⊙ h1)) ----------------
    {
        f32x4 acc2[4];
        #pragma unroll
        for (int jt = 0; jt < 4; ++jt) acc2[jt] = (f32x4){0.f, 0.f, 0.f, 0.f};
        #pragma unroll
        for (int kt = 0; kt < 4; ++kt) {
            bf16x8 a = *reinterpret_cast<const bf16x8*>(&S[(16*w + ll)*136 + kt*32 + 8*lh]);
            #pragma unroll
            for (int jt = 0; jt < 4; ++jt) {
                bf16x8 bf = *reinterpret_cast<const bf16x8*>(&H1T[(16*jt + ll)*136 + kt*32 + 8*lh]);
                acc2[jt] = __builtin_amdgcn_mfma_f32_16x16x32_bf16(a, bf, acc2[jt], 0, 0, 0);
            }
        }
        #pragma unroll
        for (int jt = 0; jt < 4; ++jt) {
            #pragma unroll
            for (int r = 0; r < 4; ++r) {
                int row = 16*w + 4*lh + r;
                AG2[row*72 + 16*jt + ll] = (__bf16)(acc2[jt][r] * DINV[row]);
            }
        }
    }
    __syncthreads();   // all H1T reads + S reads done

    // ---------------- W2T (bf16) from registers, overlaying H1T ----------------
    {
        int j = t >> 3, kb = (t & 7) * 8;
        bf16x8 pv;
        #pragma unroll
        for (int i = 0; i < 8; ++i) pv[i] = (__bf16)w2reg[i];
        *reinterpret_cast<bf16x8*>(&W2T[j*72 + kb]) = pv;
    }
    __syncthreads();

    // ---------------- M4: h = BN(elu(agg2 @ W2 + b2)) -> f32, overlays S ----------------
    {
        f32x4 acc4[4];
        #pragma unroll
        for (int jt = 0; jt < 4; ++jt) acc4[jt] = (f32x4){0.f, 0.f, 0.f, 0.f};
        #pragma unroll
        for (int kt = 0; kt < 2; ++kt) {
            bf16x8 a = *reinterpret_cast<const bf16x8*>(&AG2[(16*w + ll)*72 + kt*32 + 8*lh]);
            #pragma unroll
            for (int jt = 0; jt < 4; ++jt) {
                bf16x8 bf = *reinterpret_cast<const bf16x8*>(&W2T[(16*jt + ll)*72 + kt*32 + 8*lh]);
                acc4[jt] = __builtin_amdgcn_mfma_f32_16x16x32_bf16(a, bf, acc4[jt], 0, 0, 0);
            }
        }
        #pragma unroll
        for (int jt = 0; jt < 4; ++jt) {
            float bj = B2v[16*jt + ll];
            #pragma unroll
            for (int r = 0; r < 4; ++r) {
                int row = 16*w + 4*lh + r;
                float v = eluf(acc4[jt][r] + bj) * BNS[row] + BNB[row];
                Hf[row*68 + 16*jt + ll] = v;
            }
        }
    }
    __syncthreads();

    // ---------------- F1: attention scores + alpha_node (512 threads) ----------------
    {
        int n = t >> 2, q = t & 3;
        const float* hrow = &Hf[n*68 + q*16];
        float accA = 0.f, accN = 0.f;
        #pragma unroll
        for (int jj = 0; jj < 16; ++jj) {
            int j = (jj + n) & 15;
            float hv = hrow[j];
            accA += hv * AW[q*16 + j];
            accN += hv * NWv[q*16 + j];
        }
        accA += __shfl_xor(accA, 1); accA += __shfl_xor(accA, 2);
        accN += __shfl_xor(accN, 1); accN += __shfl_xor(accN, 2);
        if (q == 0) {
            SCv[n] = accA + attn_b[0];
            out[12288 + (size_t)b*NN + n] = softplusf(accN + na_b[0]);   // alpha_node
        }
    }
    __syncthreads();

    // ---------------- F2: softmax over nodes (wave 0) ----------------
    if (t < 64) {
        float s0 = SCv[t], s1 = SCv[64 + t];
        float mx = fmaxf(s0, s1);
        #pragma unroll
        for (int m = 32; m >= 1; m >>= 1) mx = fmaxf(mx, __shfl_xor(mx, m));
        float e0 = expf(s0 - mx), e1 = expf(s1 - mx);
        float sum = e0 + e1;
        #pragma unroll
        for (int m = 32; m >= 1; m >>= 1) sum += __shfl_xor(sum, m);
        float inv = 1.f / sum;
        float w0 = e0*inv, w1 = e1*inv;
        SCv[t]      = w0;
        SCv[64 + t] = w1;
        out[536576 + (size_t)b*NN + t]      = w0;          // weights
        out[536576 + (size_t)b*NN + 64 + t] = w1;
    }
    __syncthreads();

    // ---------------- F3: graph_emb partials (512 threads) ----------------
    {
        int c = t >> 6, j = t & 63;
        float p = 0.f;
        #pragma unroll
        for (int mm = 0; mm < 16; ++mm) {
            int m = c*16 + mm;
            p += Hf[m*68 + j] * SCv[m];
        }
        GEp[c*64 + j] = p;
    }
    __syncthreads();
    if (t < 64) {
        float ge = 0.f;
        #pragma unroll
        for (int c = 0; c < 8; ++c) ge += GEp[c*64 + t];
        INv[136 + t] = ge;
    }
    __syncthreads();

    // ---------------- G1: MLP partials (384 threads) ----------------
    if (t < 256) {
        int c = t >> 6, j = t & 63;
        float p = 0.f;
        #pragma unroll 5
        for (int i = c*50; i < c*50 + 50; ++i)
            p += INv[i] * beta_w1[i*64 + j];
        GP[c*64 + j] = p;
    } else if (t < 384) {
        int u = t - 256, c = u >> 5, j = u & 31;
        float p = 0.f;
        #pragma unroll 4
        for (int i = c*48; i < c*48 + 48; ++i) {
            float av = (i < 64) ? INv[136 + i] : INv[i - 64];
            p += av * af_w1[i*32 + j];
        }
        AP[c*32 + j] = p;
    }
    __syncthreads();

    // ---------------- G2: finish ----------------
    if (t < 64) {
        float acc = beta_b1[t] + GP[t] + GP[64 + t] + GP[128 + t] + GP[192 + t];
        float p = tanhf(acc) * beta_w2[t];
        #pragma unroll
        for (int m = 32; m >= 1; m >>= 1) p += __shfl_xor(p, m);
        if (t == 0) SCAL[0] = 1.f / (1.f + expf(-(p + beta_b2[0])));
    } else if (t < 96) {
        int u = t - 64;
        float acc = af_b1[u] + AP[u] + AP[32 + u] + AP[64 + u] + AP[96 + u];
        float p = fmaxf(acc, 0.f) * af_w2[u];
        #pragma unroll
        for (int m = 16; m >= 1; m >>= 1) p += __shfl_xor(p, m);
        if (u == 0) SCAL[1] = softplusf(p + af_b2[0]);
    }
    __syncthreads();

    if (t == 0) {
        float bet = SCAL[0], dec = SCAL[1];
        out[b]        = bet * (1.f - dec * age[b]);   // pred
        out[4096 + b] = bet;                          // beta
        out[8192 + b] = dec;                          // decay_rate
    }
}

extern "C" void kernel_launch(void* const* d_in, const int* in_sizes, int n_in,
                              void* d_out, int out_size, void* d_ws, size_t ws_size,
                              hipStream_t stream) {
    (void)in_sizes; (void)n_in; (void)out_size; (void)d_ws; (void)ws_size;
    const float* x_str   = (const float*)d_in[0];
    const float* x_raw   = (const float*)d_in[1];
    const float* adj     = (const float*)d_in[2];
    const float* x_cov   = (const float*)d_in[3];
    const float* age     = (const float*)d_in[4];
    const float* gc1_w   = (const float*)d_in[5];
    const float* gc1_b   = (const float*)d_in[6];
    const float* gc2_w   = (const float*)d_in[7];
    const float* gc2_b   = (const float*)d_in[8];
    const float* bn_g    = (const float*)d_in[9];
    const float* bn_b    = (const float*)d_in[10];
    const float* bn_m    = (const float*)d_in[11];
    const float* bn_v    = (const float*)d_in[12];
    const float* attn_w  = (const float*)d_in[13];
    const float* attn_b  = (const float*)d_in[14];
    const float* na_w    = (const float*)d_in[15];
    const float* na_b    = (const float*)d_in[16];
    const float* beta_w1 = (const float*)d_in[17];
    const float* beta_b1 = (const float*)d_in[18];
    const float* beta_w2 = (const float*)d_in[19];
    const float* beta_b2 = (const float*)d_in[20];
    const float* af_w1   = (const float*)d_in[21];
    const float* af_b1   = (const float*)d_in[22];
    const float* af_w2   = (const float*)d_in[23];
    const float* af_b2   = (const float*)d_in[24];
    float* out = (float*)d_out;

    (void)hipFuncSetAttribute((const void*)agp_kernel,
                              hipFuncAttributeMaxDynamicSharedMemorySize, SMEM_BYTES);
    agp_kernel<<<BB, 512, SMEM_BYTES, stream>>>(
        x_str, x_raw, adj, x_cov, age,
        gc1_w, gc1_b, gc2_w, gc2_b,
        bn_g, bn_b, bn_m, bn_v,
        attn_w, attn_b, na_w, na_b,
        beta_w1, beta_b1, beta_w2, beta_b2,
        af_w1, af_b1, af_w2, af_b2,
        out);
}

// Round 4
// 157.518 us; speedup vs baseline: 4.9597x; 1.1722x over previous
//
#include <hip/hip_runtime.h>
#include <hip/hip_bf16.h>
#include <math.h>

#define BB 4096
#define NN 128

typedef __attribute__((ext_vector_type(8))) __bf16 bf16x8;
typedef __attribute__((ext_vector_type(4))) float f32x4;

// ---- LDS byte offsets ----
// R1 [0,19712): phase1 XT+W1T+AG1 -> M3/M4 AG2 -> tail GEp/GP/AP/SCv
// R2 [19712,37120): H1T -> W2T
constexpr int OFF_XT   = 0;        // bf16 [16][136]  (d_inv ⊙ x)^T       (dead after M1)
constexpr int OFF_W1T  = 4352;     // bf16 [64][40]   W1^T k16..31 zeroed  (dead after M2)
constexpr int OFF_AG1  = 9472;     // bf16 [128][40]  agg1 c16..31 zeroed  (dead after M2)
constexpr int OFF_AG2  = 0;        // bf16 [128][72]  (M3 -> M4)
constexpr int OFF_GEP  = 0;        // f32 [32][64] graph-emb partials (tail)
constexpr int OFF_GP   = 8192;     // f32 [4][64] beta-MLP partials
constexpr int OFF_AP   = 9216;     // f32 [4][32] decay-MLP partials
constexpr int OFF_SCV  = 9728;     // f32 [128] attn scores -> weights
constexpr int OFF_H1T  = 19712;    // bf16 [64][136]  (d_inv ⊙ h1)^T      (dead after M3)
constexpr int OFF_W2T  = 19712;    // bf16 [64][72]   W2^T (post-M3 -> M4)
constexpr int OFF_RS   = 37120;    // f32 [128] raw rowsums (kept raw; rsqrt on the fly)
constexpr int OFF_BNS  = 37632;    // f32 [128]
constexpr int OFF_BNB  = 38144;    // f32 [128]
constexpr int OFF_AW   = 38656;    // f32 [64]
constexpr int OFF_NW   = 38912;    // f32 [64]
constexpr int OFF_GEV  = 39168;    // f32 [64] graph_emb
constexpr int OFF_SCAL = 39424;    // f32 [4]
constexpr int SMEM_BYTES = 39440;  // -> 4 blocks/CU

__device__ inline float eluf(float x)      { return x > 0.f ? x : expm1f(x); }
__device__ inline float softplusf(float x) { return (x > 20.f) ? x : log1pf(expf(x)); }

__global__ __launch_bounds__(512, 8)
void agp_kernel(const float* __restrict__ x_str, const float* __restrict__ x_raw,
                const float* __restrict__ adj,   const float* __restrict__ x_cov,
                const float* __restrict__ age,
                const float* __restrict__ gc1_w, const float* __restrict__ gc1_b,
                const float* __restrict__ gc2_w, const float* __restrict__ gc2_b,
                const float* __restrict__ bn_gamma, const float* __restrict__ bn_beta,
                const float* __restrict__ bn_mean,  const float* __restrict__ bn_var,
                const float* __restrict__ attn_w, const float* __restrict__ attn_b,
                const float* __restrict__ na_w,   const float* __restrict__ na_b,
                const float* __restrict__ beta_w1, const float* __restrict__ beta_b1,
                const float* __restrict__ beta_w2, const float* __restrict__ beta_b2,
                const float* __restrict__ af_w1,  const float* __restrict__ af_b1,
                const float* __restrict__ af_w2,  const float* __restrict__ af_b2,
                float* __restrict__ out)
{
    extern __shared__ __align__(16) char smraw[];
    __bf16* XT  = (__bf16*)(smraw + OFF_XT);
    __bf16* W1T = (__bf16*)(smraw + OFF_W1T);
    __bf16* AG1 = (__bf16*)(smraw + OFF_AG1);
    __bf16* AG2 = (__bf16*)(smraw + OFF_AG2);
    __bf16* H1T = (__bf16*)(smraw + OFF_H1T);
    __bf16* W2T = (__bf16*)(smraw + OFF_W2T);
    float* GEp  = (float*)(smraw + OFF_GEP);
    float* GP   = (float*)(smraw + OFF_GP);
    float* AP   = (float*)(smraw + OFF_AP);
    float* SCv  = (float*)(smraw + OFF_SCV);
    float* RS   = (float*)(smraw + OFF_RS);
    float* BNS  = (float*)(smraw + OFF_BNS);
    float* BNB  = (float*)(smraw + OFF_BNB);
    float* AW   = (float*)(smraw + OFF_AW);
    float* NWv  = (float*)(smraw + OFF_NW);
    float* GEv  = (float*)(smraw + OFF_GEV);
    float* SCAL = (float*)(smraw + OFF_SCAL);

    const int b = blockIdx.x;
    const int t = threadIdx.x;
    const int w    = t >> 6;
    const int lane = t & 63;
    const int ll = lane & 15;
    const int lh = lane >> 4;
    const int myrow = 16*w + ll;

    // ---------------- A0: adj -> registers (A-fragment layout) + rowsum; stage weights ----------------
    bf16x8 sf[4];
    {
        const float* arow = adj + (size_t)b*NN*NN + (size_t)myrow*NN;
        float rs = 0.f;
        #pragma unroll
        for (int kt = 0; kt < 4; ++kt) {
            int c0 = kt*32 + 8*lh;
            float4 a  = *reinterpret_cast<const float4*>(arow + c0);
            float4 a2 = *reinterpret_cast<const float4*>(arow + c0 + 4);
            a.x  += (c0+0==myrow)?1.f:0.f; a.y  += (c0+1==myrow)?1.f:0.f;
            a.z  += (c0+2==myrow)?1.f:0.f; a.w  += (c0+3==myrow)?1.f:0.f;
            a2.x += (c0+4==myrow)?1.f:0.f; a2.y += (c0+5==myrow)?1.f:0.f;
            a2.z += (c0+6==myrow)?1.f:0.f; a2.w += (c0+7==myrow)?1.f:0.f;
            rs += ((a.x+a.y)+(a.z+a.w)) + ((a2.x+a2.y)+(a2.z+a2.w));
            bf16x8 s;
            s[0]=(__bf16)a.x;  s[1]=(__bf16)a.y;  s[2]=(__bf16)a.z;  s[3]=(__bf16)a.w;
            s[4]=(__bf16)a2.x; s[5]=(__bf16)a2.y; s[6]=(__bf16)a2.z; s[7]=(__bf16)a2.w;
            sf[kt] = s;
        }
        rs += __shfl_xor(rs, 16);
        rs += __shfl_xor(rs, 32);
        if (lh == 0) RS[myrow] = rs;      // raw rowsum (f32, pre-truncation)
    }
    float4 xv = reinterpret_cast<const float4*>(x_str + (size_t)b*NN*16)[t];
    for (int idx = t; idx < 1024; idx += 512) {            // W1^T
        int k = idx >> 6, j = idx & 63;
        W1T[j*40 + k] = (__bf16)gc1_w[idx];
    }
    for (int idx = t; idx < 1024; idx += 512) {            // W1^T zero pad k=16..31
        int j = idx >> 4, k = idx & 15;
        W1T[j*40 + 16 + k] = (__bf16)0.f;
    }
    for (int idx = t; idx < 2048; idx += 512) {            // AG1 zero pad c=16..31
        int r = idx >> 4, c = idx & 15;
        AG1[r*40 + 16 + c] = (__bf16)0.f;
    }
    if (t < 128) {
        float g = bn_gamma[t], be = bn_beta[t], mu = bn_mean[t], va = bn_var[t];
        float sc = g * rsqrtf(va + 1e-5f);
        BNS[t] = sc;
        BNB[t] = be - mu*sc;
    } else if (t < 192) {
        AW[t-128] = attn_w[t-128];
    } else if (t < 256) {
        NWv[t-192] = na_w[t-192];
    }
    __syncthreads();   // bar1

    // ---------------- A1: XT = (d_inv ⊙ x)^T ----------------
    {
        int m = t >> 2;
        float dm = rsqrtf(RS[m]);             // rowsum >= 1, never inf
        int c0 = (t & 3) * 4;
        XT[(c0+0)*136 + m] = (__bf16)(xv.x * dm);
        XT[(c0+1)*136 + m] = (__bf16)(xv.y * dm);
        XT[(c0+2)*136 + m] = (__bf16)(xv.z * dm);
        XT[(c0+3)*136 + m] = (__bf16)(xv.w * dm);
    }
    __syncthreads();   // bar2

    // ---------------- M1: agg1 = d_r ⊙ (A_hat @ (d_c ⊙ x)) ----------------
    float dr[4];
    {
        f32x4 acc = {0.f, 0.f, 0.f, 0.f};
        #pragma unroll
        for (int kt = 0; kt < 4; ++kt) {
            bf16x8 bf = *reinterpret_cast<const bf16x8*>(&XT[ll*136 + kt*32 + 8*lh]);
            acc = __builtin_amdgcn_mfma_f32_16x16x32_bf16(sf[kt], bf, acc, 0, 0, 0);
        }
        #pragma unroll
        for (int r = 0; r < 4; ++r) {
            int row = 16*w + 4*lh + r;
            dr[r] = rsqrtf(RS[row]);
            AG1[row*40 + ll] = (__bf16)(acc[r] * dr[r]);
        }
    }
    __syncthreads();   // bar3

    // ---------------- M2: h1 = elu(agg1 @ W1 + b1); H1T = (d_inv ⊙ h1)^T ----------------
    {
        bf16x8 a = *reinterpret_cast<const bf16x8*>(&AG1[(16*w + ll)*40 + 8*lh]);
        #pragma unroll
        for (int jt = 0; jt < 4; ++jt) {
            bf16x8 bf = *reinterpret_cast<const bf16x8*>(&W1T[(16*jt + ll)*40 + 8*lh]);
            f32x4 z = {0.f, 0.f, 0.f, 0.f};
            f32x4 acc = __builtin_amdgcn_mfma_f32_16x16x32_bf16(a, bf, z, 0, 0, 0);
            float bj = gc1_b[16*jt + ll];
            #pragma unroll
            for (int r = 0; r < 4; ++r) {
                int m = 16*w + 4*lh + r;
                float v = eluf(acc[r] + bj);
                H1T[(16*jt + ll)*136 + m] = (__bf16)(v * dr[r]);
            }
        }
    }
    __syncthreads();   // bar4

    // ---------------- M3: agg2 = d_r ⊙ (A_hat @ (d_c ⊙ h1)) ----------------
    {
        f32x4 acc2[4];
        #pragma unroll
        for (int jt = 0; jt < 4; ++jt) acc2[jt] = (f32x4){0.f, 0.f, 0.f, 0.f};
        #pragma unroll
        for (int kt = 0; kt < 4; ++kt) {
            #pragma unroll
            for (int jt = 0; jt < 4; ++jt) {
                bf16x8 bf = *reinterpret_cast<const bf16x8*>(&H1T[(16*jt + ll)*136 + kt*32 + 8*lh]);
                acc2[jt] = __builtin_amdgcn_mfma_f32_16x16x32_bf16(sf[kt], bf, acc2[jt], 0, 0, 0);
            }
        }
        #pragma unroll
        for (int jt = 0; jt < 4; ++jt) {
            #pragma unroll
            for (int r = 0; r < 4; ++r) {
                int row = 16*w + 4*lh + r;
                AG2[row*72 + 16*jt + ll] = (__bf16)(acc2[jt][r] * dr[r]);
            }
        }
    }
    // W2 gather -> regs (overlaps barrier wait)
    float w2r[8];
    {
        int j = t >> 3, kb = (t & 7) * 8;
        #pragma unroll
        for (int i = 0; i < 8; ++i) w2r[i] = gc2_w[(kb + i)*64 + j];
    }
    __syncthreads();   // bar5: all H1T reads done
    {
        int j = t >> 3, kb = (t & 7) * 8;
        bf16x8 pv;
        #pragma unroll
        for (int i = 0; i < 8; ++i) pv[i] = (__bf16)w2r[i];
        *reinterpret_cast<bf16x8*>(&W2T[j*72 + kb]) = pv;
    }
    __syncthreads();   // bar6

    // ---------------- M4: h = BN(elu(agg2 @ W2 + b2)) -> stays in registers ----------------
    f32x4 hv[4];
    {
        #pragma unroll
        for (int jt = 0; jt < 4; ++jt) hv[jt] = (f32x4){0.f, 0.f, 0.f, 0.f};
        #pragma unroll
        for (int kt = 0; kt < 2; ++kt) {
            bf16x8 a = *reinterpret_cast<const bf16x8*>(&AG2[(16*w + ll)*72 + kt*32 + 8*lh]);
            #pragma unroll
            for (int jt = 0; jt < 4; ++jt) {
                bf16x8 bf = *reinterpret_cast<const bf16x8*>(&W2T[(16*jt + ll)*72 + kt*32 + 8*lh]);
                hv[jt] = __builtin_amdgcn_mfma_f32_16x16x32_bf16(a, bf, hv[jt], 0, 0, 0);
            }
        }
        float bns[4], bnb_[4];
        #pragma unroll
        for (int r = 0; r < 4; ++r) {
            int row = 16*w + 4*lh + r;
            bns[r] = BNS[row]; bnb_[r] = BNB[row];
        }
        #pragma unroll
        for (int jt = 0; jt < 4; ++jt) {
            float bj = gc2_b[16*jt + ll];
            #pragma unroll
            for (int r = 0; r < 4; ++r)
                hv[jt][r] = eluf(hv[jt][r] + bj) * bns[r] + bnb_[r];
        }
    }
    __syncthreads();   // bar7: AG2/W2T reads done before SCv write below

    // ---------------- F1: attention scores + alpha_node from registers ----------------
    {
        float aA[4] = {0,0,0,0}, aN[4] = {0,0,0,0};
        #pragma unroll
        for (int jt = 0; jt < 4; ++jt) {
            float wA = AW[16*jt + ll], wN = NWv[16*jt + ll];
            #pragma unroll
            for (int r = 0; r < 4; ++r) {
                aA[r] += hv[jt][r] * wA;
                aN[r] += hv[jt][r] * wN;
            }
        }
        #pragma unroll
        for (int m = 1; m <= 8; m <<= 1) {
            #pragma unroll
            for (int r = 0; r < 4; ++r) {
                aA[r] += __shfl_xor(aA[r], m);
                aN[r] += __shfl_xor(aN[r], m);
            }
        }
        if (ll == 0) {
            float sA = attn_b[0], sN = na_b[0];
            #pragma unroll
            for (int r = 0; r < 4; ++r) {
                int row = 16*w + 4*lh + r;
                SCv[row] = aA[r] + sA;
                out[12288 + (size_t)b*NN + row] = softplusf(aN[r] + sN);   // alpha_node
            }
        }
    }
    __syncthreads();   // bar8

    // ---------------- F2: softmax over nodes (wave 0) ----------------
    if (t < 64) {
        float s0 = SCv[t], s1 = SCv[64 + t];
        float mx = fmaxf(s0, s1);
        #pragma unroll
        for (int m = 32; m >= 1; m >>= 1) mx = fmaxf(mx, __shfl_xor(mx, m));
        float e0 = expf(s0 - mx), e1 = expf(s1 - mx);
        float sum = e0 + e1;
        #pragma unroll
        for (int m = 32; m >= 1; m >>= 1) sum += __shfl_xor(sum, m);
        float inv = 1.f / sum;
        float w0 = e0*inv, w1 = e1*inv;
        SCv[t]      = w0;
        SCv[64 + t] = w1;
        out[536576 + (size_t)b*NN + t]      = w0;          // weights
        out[536576 + (size_t)b*NN + 64 + t] = w1;
    }
    __syncthreads();   // bar9

    // ---------------- F3: graph_emb partials from registers ----------------
    {
        float wt[4];
        #pragma unroll
        for (int r = 0; r < 4; ++r) wt[r] = SCv[16*w + 4*lh + r];
        #pragma unroll
        for (int jt = 0; jt < 4; ++jt) {
            float g = 0.f;
            #pragma unroll
            for (int r = 0; r < 4; ++r) g += hv[jt][r] * wt[r];
            GEp[(4*w + lh)*64 + 16*jt + ll] = g;
        }
    }
    __syncthreads();   // bar10
    if (t < 64) {
        float ge = 0.f;
        #pragma unroll
        for (int g = 0; g < 32; ++g) ge += GEp[g*64 + t];
        GEv[t] = ge;
    }
    __syncthreads();   // bar11

    // ---------------- G1: MLP partials ----------------
    if (t < 256) {
        int c = t >> 6, j = t & 63;
        float p = 0.f;
        for (int i = c*50; i < c*50 + 50; ++i) {
            float v = (i < 128) ? x_raw[(size_t)b*128 + i]
                    : (i < 136) ? x_cov[(size_t)b*8 + (i - 128)]
                                : GEv[i - 136];
            p += v * beta_w1[i*64 + j];
        }
        GP[c*64 + j] = p;
    } else if (t < 384) {
        int u = t - 256, c = u >> 5, j = u & 31;
        float p = 0.f;
        for (int i = c*48; i < c*48 + 48; ++i) {
            float v = (i < 64) ? GEv[i] : x_raw[(size_t)b*128 + (i - 64)];
            p += v * af_w1[i*32 + j];
        }
        AP[c*32 + j] = p;
    }
    __syncthreads();   // bar12

    // ---------------- G2: finish ----------------
    if (t < 64) {
        float acc = beta_b1[t] + GP[t] + GP[64 + t] + GP[128 + t] + GP[192 + t];
        float p = tanhf(acc) * beta_w2[t];
        #pragma unroll
        for (int m = 32; m >= 1; m >>= 1) p += __shfl_xor(p, m);
        if (t == 0) SCAL[0] = 1.f / (1.f + expf(-(p + beta_b2[0])));
    } else if (t < 96) {
        int u = t - 64;
        float acc = af_b1[u] + AP[u] + AP[32 + u] + AP[64 + u] + AP[96 + u];
        float p = fmaxf(acc, 0.f) * af_w2[u];
        #pragma unroll
        for (int m = 16; m >= 1; m >>= 1) p += __shfl_xor(p, m);
        if (u == 0) SCAL[1] = softplusf(p + af_b2[0]);
    }
    __syncthreads();   // bar13

    if (t == 0) {
        float bet = SCAL[0], dec = SCAL[1];
        out[b]        = bet * (1.f - dec * age[b]);   // pred
        out[4096 + b] = bet;                          // beta
        out[8192 + b] = dec;                          // decay_rate
    }
}

extern "C" void kernel_launch(void* const* d_in, const int* in_sizes, int n_in,
                              void* d_out, int out_size, void* d_ws, size_t ws_size,
                              hipStream_t stream) {
    (void)in_sizes; (void)n_in; (void)out_size; (void)d_ws; (void)ws_size;
    const float* x_str   = (const float*)d_in[0];
    const float* x_raw   = (const float*)d_in[1];
    const float* adj     = (const float*)d_in[2];
    const float* x_cov   = (const float*)d_in[3];
    const float* age     = (const float*)d_in[4];
    const float* gc1_w   = (const float*)d_in[5];
    const float* gc1_b   = (const float*)d_in[6];
    const float* gc2_w   = (const float*)d_in[7];
    const float* gc2_b   = (const float*)d_in[8];
    const float* bn_g    = (const float*)d_in[9];
    const float* bn_b    = (const float*)d_in[10];
    const float* bn_m    = (const float*)d_in[11];
    const float* bn_v    = (const float*)d_in[12];
    const float* attn_w  = (const float*)d_in[13];
    const float* attn_b  = (const float*)d_in[14];
    const float* na_w    = (const float*)d_in[15];
    const float* na_b    = (const float*)d_in[16];
    const float* beta_w1 = (const float*)d_in[17];
    const float* beta_b1 = (const float*)d_in[18];
    const float* beta_w2 = (const float*)d_in[19];
    const float* beta_b2 = (const float*)d_in[20];
    const float* af_w1   = (const float*)d_in[21];
    const float* af_b1   = (const float*)d_in[22];
    const float* af_w2   = (const float*)d_in[23];
    const float* af_b2   = (const float*)d_in[24];
    float* out = (float*)d_out;

    (void)hipFuncSetAttribute((const void*)agp_kernel,
                              hipFuncAttributeMaxDynamicSharedMemorySize, SMEM_BYTES);
    agp_kernel<<<BB, 512, SMEM_BYTES, stream>>>(
        x_str, x_raw, adj, x_cov, age,
        gc1_w, gc1_b, gc2_w, gc2_b,
        bn_g, bn_b, bn_m, bn_v,
        attn_w, attn_b, na_w, na_b,
        beta_w1, beta_b1, beta_w2, beta_b2,
        af_w1, af_b1, af_w2, af_b2,
        out);
}